// Round 7
// baseline (176.273 us; speedup 1.0000x reference)
//
#include <hip/hip_runtime.h>
#include <math.h>

#define D 64
#define MIN_NORM 1e-15f
#define PROJ_MAXNORM 0.996f   // (1 - 4e-3) / sqrt(c), c=1
#define RPB 128               // rows per bin (8 waves x 16 rows/wave)
#define BINCAP 2560           // bin edge capacity: Binomial mean 2048 + 11 sigma
#define MAXBIN 1024           // LDS histogram capacity (nbins = ceil(N/128) = 782)
#define EPB 4096              // edges per binning block -> 391 blocks
#define BT 512                // block threads (8 waves)

typedef __attribute__((ext_vector_type(8))) short short8;   // 8 bf16 (4 VGPR)
typedef __attribute__((ext_vector_type(4))) float float4_;  // MFMA C/D

// artanh for z >= 0 (input is a norm), fast log + rcp
__device__ __forceinline__ float fast_artanh(float z) {
    z = fminf(z, 1.0f - 1e-7f);
    return 0.5f * __logf((1.0f + z) * __builtin_amdgcn_rcpf(1.0f - z));
}

__device__ __forceinline__ unsigned short f2bf(float x) {  // RNE
    unsigned int b = __float_as_uint(x);
    return (unsigned short)((b + 0x7fffu + ((b >> 16) & 1u)) >> 16);
}

__device__ __forceinline__ float bf2f(unsigned short u) {
    return __uint_as_float(((unsigned int)u) << 16);
}

// Kernel 1 (fat): edge-blocks do two-level binning (LDS histogram of 128-row
// bins -> one global atomic per (block,bin) to reserve a range -> packed
// (row_local:7 | col:17) stores in contiguous per-bin runs). Node-blocks do
// the BW-bound prep (bf16 copy + (sqnorm, logmap0-scale)). R5-proven; only
// the bin width changed (64->128 rows, shift 6->7).
__global__ void bin_kernel(const float* __restrict__ x,
                           unsigned short* __restrict__ x_bf,
                           float2* __restrict__ snf,
                           const int* __restrict__ row_idx,
                           const int* __restrict__ col_idx,
                           int* __restrict__ cursor,
                           unsigned int* __restrict__ binData,
                           int E, int N, int nbins, int edgeBlocks) {
    __shared__ int hist[MAXBIN];
    __shared__ int base[MAXBIN];
    if ((int)blockIdx.x < edgeBlocks) {
        int e0 = blockIdx.x * EPB;
        int e1 = min(E, e0 + EPB);
        for (int i = threadIdx.x; i < nbins; i += BT) hist[i] = 0;
        __syncthreads();
        // pass 1: LDS histogram of bins (int4-coalesced row reads)
        if (e1 - e0 == EPB) {
#pragma unroll
            for (int it = 0; it < EPB / (BT * 4); ++it) {
                int4 r = *(const int4*)(row_idx + e0 + it * (BT * 4) + (int)threadIdx.x * 4);
                atomicAdd(&hist[r.x >> 7], 1);
                atomicAdd(&hist[r.y >> 7], 1);
                atomicAdd(&hist[r.z >> 7], 1);
                atomicAdd(&hist[r.w >> 7], 1);
            }
        } else {
            for (int e = e0 + (int)threadIdx.x; e < e1; e += BT)
                atomicAdd(&hist[row_idx[e] >> 7], 1);
        }
        __syncthreads();
        // pass 2: reserve global ranges, one atomic per touched bin;
        // base[] becomes the running within-bin cursor for pass 3
        for (int i = threadIdx.x; i < nbins; i += BT) {
            int h = hist[i];
            base[i] = h ? atomicAdd(&cursor[i], h) : 0;
        }
        __syncthreads();
        // pass 3: place packed edges at reserved offsets (contiguous runs)
        if (e1 - e0 == EPB) {
#pragma unroll
            for (int it = 0; it < EPB / (BT * 4); ++it) {
                int o = e0 + it * (BT * 4) + (int)threadIdx.x * 4;
                int4 r = *(const int4*)(row_idx + o);
                int4 c = *(const int4*)(col_idx + o);
                int b0 = r.x >> 7, b1 = r.y >> 7, b2 = r.z >> 7, b3 = r.w >> 7;
                int k0 = atomicAdd(&base[b0], 1);
                int k1 = atomicAdd(&base[b1], 1);
                int k2 = atomicAdd(&base[b2], 1);
                int k3 = atomicAdd(&base[b3], 1);
                if (k0 < BINCAP) binData[(size_t)b0 * BINCAP + k0] = ((unsigned int)(r.x & 127) << 17) | (unsigned int)c.x;
                if (k1 < BINCAP) binData[(size_t)b1 * BINCAP + k1] = ((unsigned int)(r.y & 127) << 17) | (unsigned int)c.y;
                if (k2 < BINCAP) binData[(size_t)b2 * BINCAP + k2] = ((unsigned int)(r.z & 127) << 17) | (unsigned int)c.z;
                if (k3 < BINCAP) binData[(size_t)b3 * BINCAP + k3] = ((unsigned int)(r.w & 127) << 17) | (unsigned int)c.w;
            }
        } else {
            for (int e = e0 + (int)threadIdx.x; e < e1; e += BT) {
                int r = row_idx[e];
                int c = col_idx[e];
                int b = r >> 7;
                int rk = atomicAdd(&base[b], 1);
                if (rk < BINCAP)
                    binData[(size_t)b * BINCAP + rk] =
                        ((unsigned int)(r & 127) << 17) | (unsigned int)c;
            }
        }
    } else {
        // ---- prep role: 32 nodes/block, float4 loads, ushort4 stores ----
        int nb = blockIdx.x - edgeBlocks;
        int node = nb * (BT / 16) + ((int)threadIdx.x >> 4);
        int j = threadIdx.x & 15;
        if (node >= N) return;
        float4 v = *((const float4*)(x + (size_t)node * D) + j);
        float s = v.x * v.x + v.y * v.y + v.z * v.z + v.w * v.w;
#pragma unroll
        for (int m = 1; m < 16; m <<= 1)
            s += __shfl_xor(s, m, 64);   // reduce within aligned 16-lane group
        float pn = fmaxf(sqrtf(s), MIN_NORM);
        float f = fast_artanh(pn) / pn;
        ushort4 o;
        o.x = f2bf(v.x); o.y = f2bf(v.y); o.z = f2bf(v.z); o.w = f2bf(v.w);
        *((ushort4*)(x_bf + (size_t)node * D) + j) = o;
        if (j == 0) snf[node] = make_float2(s, f);
    }
}

// Kernel 2: one block per 128-row bin, 8 waves, 16 ROWS PER WAVE.
// The 16 MFMA B-columns now carry 16 DIFFERENT rows (was: 1 row replicated
// 16x). Chunk = one edge from each of the wave's 16 rows; lane (qd,jj) owns
// row jj's edge. Needed dot = D[jj][jj], extracted by the SAME sel+shfl(src)
// as before. Weight math verbatim. acc per lane = row jj's complete feature
// slice -> the 15-shfl butterfly / wacc reduce / wave reduce all vanish;
// per-row prologue amortizes /16.
__global__ void fused_kernel(const unsigned short* __restrict__ x_bf,
                             const float2* __restrict__ snf,
                             const unsigned int* __restrict__ binData,
                             const int* __restrict__ cursor,
                             const float* __restrict__ beta,
                             const float* __restrict__ con,
                             float* __restrict__ out, int N) {
    __shared__ int cnt[RPB];
    __shared__ int off[RPB];
    __shared__ int cur[RPB];
    __shared__ int tot[2];
    __shared__ int colsm[BINCAP];

    int b = blockIdx.x;
    int len = min(cursor[b], BINCAP);
    const unsigned int* bd = binData + (size_t)b * BINCAP;

    if (threadIdx.x < RPB) { cnt[threadIdx.x] = 0; cur[threadIdx.x] = 0; }
    if (threadIdx.x == 0) colsm[0] = 0;   // safe slot for all-empty paranoia
    __syncthreads();
    for (int i = threadIdx.x; i < len; i += BT)
        atomicAdd(&cnt[bd[i] >> 17], 1);
    __syncthreads();
    if (threadIdx.x < RPB) {   // two-wave exclusive scan of cnt[128]
        int v = cnt[threadIdx.x], inc = v;
#pragma unroll
        for (int m = 1; m < 64; m <<= 1) {
            int t = __shfl_up(inc, m, 64);
            if (((int)threadIdx.x & 63) >= m) inc += t;
        }
        off[threadIdx.x] = inc - v;
        if (((int)threadIdx.x & 63) == 63) tot[threadIdx.x >> 6] = inc;
    }
    __syncthreads();
    if (threadIdx.x >= 64 && threadIdx.x < RPB) off[threadIdx.x] += tot[0];
    __syncthreads();
    for (int i = threadIdx.x; i < len; i += BT) {
        unsigned int p = bd[i];
        int rl = p >> 17;
        int rk = atomicAdd(&cur[rl], 1);
        colsm[off[rl] + rk] = (int)(p & 0x1FFFFu);
    }
    __syncthreads();

    int wid = threadIdx.x >> 6;          // wave = 16-row group, 0..7
    int lane = threadIdx.x & 63;
    int jj = lane & 15;
    int qd = lane >> 4;
    int src = ((jj >> 2) << 4) | jj;     // lane holding D[jj][jj] reg (jj&3)
    float Bc = beta[0], C0 = con[0];
    float4_ zero4 = {0.0f, 0.0f, 0.0f, 0.0f};

    int rl = wid * 16 + jj;
    int row = b * RPB + rl;              // my row (4 quad-redundant copies)
    int rlen = cnt[rl];
    int start = off[rl];
    int safe = rlen > 0 ? start + rlen - 1 : 0;

    // wave-uniform chunk count = max row length over the 16-lane group
    int ml = rlen;
#pragma unroll
    for (int m = 1; m < 16; m <<= 1)
        ml = max(ml, __shfl_xor(ml, m, 64));

    // B operand: lane (qd,jj) holds row jj's features [qd*8,+8) and [32+qd*8,+8)
    const unsigned short* xr = x_bf + (size_t)row * D + qd * 8;
    short8 bfr0 = *(const short8*)xr;    // row>=N: stale-but-allocated, unused
    short8 bfr1 = *(const short8*)(xr + 32);
    float x2 = snf[row].x;

    float acc[16];
#pragma unroll
    for (int i = 0; i < 16; i++) acc[i] = 0.0f;
    float wacc = 0.0f;

    for (int t = 0; t < ml; ++t) {
        bool valid = t < rlen;
        int cw = colsm[valid ? start + t : safe];
        const unsigned short* rp = x_bf + (size_t)cw * D + qd * 8;
        short8 af0 = *(const short8*)rp;          // col feats [qd*8, +8)
        short8 af1 = *(const short8*)(rp + 32);   // col feats [32+qd*8, +8)
        float2 sf = snf[cw];                      // (y2, f_col)

        float4_ d4 = __builtin_amdgcn_mfma_f32_16x16x32_bf16(af0, bfr0, zero4, 0, 0, 0);
        d4 = __builtin_amdgcn_mfma_f32_16x16x32_bf16(af1, bfr1, d4, 0, 0, 0);
        // D[m][n] = dot(col_of_row_m's_edge, row_n); we need D[jj][jj]

        float sel01 = (jj & 1) ? d4[1] : d4[0];
        float sel23 = (jj & 1) ? d4[3] : d4[2];
        float dsel  = (jj & 2) ? sel23 : sel01;   // my d4[jj&3]
        float d = __shfl(dsel, src, 64);          // = D[jj][jj]

        // weight math: verbatim; all 4 quads of jj compute the same w
        float y2 = sf.x;
        float a_ = 1.0f - 2.0f * d + y2;
        float b_ = 1.0f - x2;
        float num2 = a_ * a_ * x2 - 2.0f * a_ * b_ * d + b_ * b_ * y2;
        float den = fmaxf(1.0f - 2.0f * d + x2 * y2, MIN_NORM);
        float man = sqrtf(fmaxf(num2, 0.0f)) * __builtin_amdgcn_rcpf(den);
        float at = fast_artanh(man);
        float w = __expf(-Bc * 4.0f * at * at + C0);  // dist^2 = 4*artanh^2
        w = valid ? w : 0.0f;
        float wf = w * sf.y;
        wacc += w;
#pragma unroll
        for (int j = 0; j < 8; j++) {
            acc[j]     += wf * bf2f((unsigned short)af0[j]);
            acc[8 + j] += wf * bf2f((unsigned short)af1[j]);
        }
    }

    // epilogue: acc is row jj's COMPLETE slice; norm needs only a 2-shfl
    // reduce across the 4 quads (features qd*8..+8 and 32+qd*8..+8 disjoint).
    float inv = __builtin_amdgcn_rcpf(wacc + 1e-10f);
    float s[16];
    float loc = 0.0f;
#pragma unroll
    for (int j = 0; j < 16; j++) {
        s[j] = acc[j] * inv;
        loc += s[j] * s[j];
    }
    loc += __shfl_xor(loc, 16, 64);
    loc += __shfl_xor(loc, 32, 64);
    float n2 = loc;
    float sq = sqrtf(n2);
    float un = fmaxf(sq, MIN_NORM);
    float e2 = __expf(2.0f * un);        // tanh via exp
    float th = (e2 - 1.0f) * __builtin_amdgcn_rcpf(e2 + 1.0f);
    float tt = th * __builtin_amdgcn_rcpf(un);
    float on = th * sq * __builtin_amdgcn_rcpf(un);   // ||o|| = tt*sq
    float scale = tt;
    if (on > PROJ_MAXNORM)
        scale = tt / fmaxf(on, MIN_NORM) * PROJ_MAXNORM;

    if (row < N) {
        float* op = out + (size_t)row * D;
        float4 v0 = make_float4(scale * s[0],  scale * s[1],  scale * s[2],  scale * s[3]);
        float4 v1 = make_float4(scale * s[4],  scale * s[5],  scale * s[6],  scale * s[7]);
        float4 v2 = make_float4(scale * s[8],  scale * s[9],  scale * s[10], scale * s[11]);
        float4 v3 = make_float4(scale * s[12], scale * s[13], scale * s[14], scale * s[15]);
        *(float4*)(op + qd * 8)          = v0;
        *(float4*)(op + qd * 8 + 4)      = v1;
        *(float4*)(op + 32 + qd * 8)     = v2;
        *(float4*)(op + 32 + qd * 8 + 4) = v3;
    }
}

extern "C" void kernel_launch(void* const* d_in, const int* in_sizes, int n_in,
                              void* d_out, int out_size, void* d_ws, size_t ws_size,
                              hipStream_t stream) {
    const float* x    = (const float*)d_in[0];
    const float* beta = (const float*)d_in[1];
    const float* con  = (const float*)d_in[2];
    const int*   ei   = (const int*)d_in[3];

    int N = in_sizes[0] / D;
    int E = in_sizes[3] / 2;
    const int* row_idx = ei;
    const int* col_idx = ei + E;
    float* out = (float*)d_out;

    int nbins = (N + RPB - 1) / RPB;    // 782 for N=100K (<= MAXBIN)

    // workspace layout (8B-aligned first): ~21.6 MB
    float2*         snf     = (float2*)d_ws;                 // N float2 (800KB)
    unsigned short* x_bf    = (unsigned short*)(snf + N);    // N*D bf16 (12.8 MB)
    unsigned int*   binData = (unsigned int*)(x_bf + (size_t)N * D); // nbins*BINCAP (7.6 MB)
    int*            cursor  = (int*)(binData + (size_t)nbins * BINCAP); // nbins ints (3 KB)

    hipMemsetAsync(cursor, 0, (size_t)nbins * sizeof(int), stream);

    int edgeBlocks = (E + EPB - 1) / EPB;              // 391 for E=1.6M
    int nodeBlocks = (N + (BT / 16) - 1) / (BT / 16);  // 3125

    bin_kernel<<<edgeBlocks + nodeBlocks, BT, 0, stream>>>(
        x, x_bf, snf, row_idx, col_idx, cursor, binData, E, N, nbins, edgeBlocks);

    fused_kernel<<<nbins, BT, 0, stream>>>(x_bf, snf, binData, cursor,
                                           beta, con, out, N);
}

// Round 8
// 166.265 us; speedup vs baseline: 1.0602x; 1.0602x over previous
//
#include <hip/hip_runtime.h>
#include <math.h>

#define D 64
#define MIN_NORM 1e-15f
#define PROJ_MAXNORM 0.996f   // (1 - 4e-3) / sqrt(c), c=1
#define RPB 128               // rows per bin (8 waves x 16 rows/wave)
#define BINCAP 2560           // bin edge capacity: Binomial mean 2048 + 11 sigma
#define MAXBIN 1024           // LDS histogram capacity (nbins = ceil(N/128) = 782)
#define EPB 4096              // edges per binning block -> 391 blocks
#define BT 512                // block threads (8 waves)

typedef __attribute__((ext_vector_type(8))) short short8;   // 8 bf16 (4 VGPR)
typedef __attribute__((ext_vector_type(4))) float float4_;  // MFMA C/D

// artanh for z >= 0 (input is a norm), fast log + rcp
__device__ __forceinline__ float fast_artanh(float z) {
    z = fminf(z, 1.0f - 1e-7f);
    return 0.5f * __logf((1.0f + z) * __builtin_amdgcn_rcpf(1.0f - z));
}

__device__ __forceinline__ unsigned short f2bf(float x) {  // RNE
    unsigned int b = __float_as_uint(x);
    return (unsigned short)((b + 0x7fffu + ((b >> 16) & 1u)) >> 16);
}

__device__ __forceinline__ float bf2f(unsigned short u) {
    return __uint_as_float(((unsigned int)u) << 16);
}

// Kernel 1 (fat): edge-blocks do two-level binning (LDS histogram of 128-row
// bins -> one global atomic per (block,bin) to reserve a range -> packed
// (row_local:7 | col:17) stores in contiguous per-bin runs). Node-blocks do
// the BW-bound prep (bf16 copy + (sqnorm, logmap0-scale)). R7-verbatim.
__global__ void bin_kernel(const float* __restrict__ x,
                           unsigned short* __restrict__ x_bf,
                           float2* __restrict__ snf,
                           const int* __restrict__ row_idx,
                           const int* __restrict__ col_idx,
                           int* __restrict__ cursor,
                           unsigned int* __restrict__ binData,
                           int E, int N, int nbins, int edgeBlocks) {
    __shared__ int hist[MAXBIN];
    __shared__ int base[MAXBIN];
    if ((int)blockIdx.x < edgeBlocks) {
        int e0 = blockIdx.x * EPB;
        int e1 = min(E, e0 + EPB);
        for (int i = threadIdx.x; i < nbins; i += BT) hist[i] = 0;
        __syncthreads();
        // pass 1: LDS histogram of bins (int4-coalesced row reads)
        if (e1 - e0 == EPB) {
#pragma unroll
            for (int it = 0; it < EPB / (BT * 4); ++it) {
                int4 r = *(const int4*)(row_idx + e0 + it * (BT * 4) + (int)threadIdx.x * 4);
                atomicAdd(&hist[r.x >> 7], 1);
                atomicAdd(&hist[r.y >> 7], 1);
                atomicAdd(&hist[r.z >> 7], 1);
                atomicAdd(&hist[r.w >> 7], 1);
            }
        } else {
            for (int e = e0 + (int)threadIdx.x; e < e1; e += BT)
                atomicAdd(&hist[row_idx[e] >> 7], 1);
        }
        __syncthreads();
        // pass 2: reserve global ranges, one atomic per touched bin;
        // base[] becomes the running within-bin cursor for pass 3
        for (int i = threadIdx.x; i < nbins; i += BT) {
            int h = hist[i];
            base[i] = h ? atomicAdd(&cursor[i], h) : 0;
        }
        __syncthreads();
        // pass 3: place packed edges at reserved offsets (contiguous runs)
        if (e1 - e0 == EPB) {
#pragma unroll
            for (int it = 0; it < EPB / (BT * 4); ++it) {
                int o = e0 + it * (BT * 4) + (int)threadIdx.x * 4;
                int4 r = *(const int4*)(row_idx + o);
                int4 c = *(const int4*)(col_idx + o);
                int b0 = r.x >> 7, b1 = r.y >> 7, b2 = r.z >> 7, b3 = r.w >> 7;
                int k0 = atomicAdd(&base[b0], 1);
                int k1 = atomicAdd(&base[b1], 1);
                int k2 = atomicAdd(&base[b2], 1);
                int k3 = atomicAdd(&base[b3], 1);
                if (k0 < BINCAP) binData[(size_t)b0 * BINCAP + k0] = ((unsigned int)(r.x & 127) << 17) | (unsigned int)c.x;
                if (k1 < BINCAP) binData[(size_t)b1 * BINCAP + k1] = ((unsigned int)(r.y & 127) << 17) | (unsigned int)c.y;
                if (k2 < BINCAP) binData[(size_t)b2 * BINCAP + k2] = ((unsigned int)(r.z & 127) << 17) | (unsigned int)c.z;
                if (k3 < BINCAP) binData[(size_t)b3 * BINCAP + k3] = ((unsigned int)(r.w & 127) << 17) | (unsigned int)c.w;
            }
        } else {
            for (int e = e0 + (int)threadIdx.x; e < e1; e += BT) {
                int r = row_idx[e];
                int c = col_idx[e];
                int b = r >> 7;
                int rk = atomicAdd(&base[b], 1);
                if (rk < BINCAP)
                    binData[(size_t)b * BINCAP + rk] =
                        ((unsigned int)(r & 127) << 17) | (unsigned int)c;
            }
        }
    } else {
        // ---- prep role: 32 nodes/block, float4 loads, ushort4 stores ----
        int nb = blockIdx.x - edgeBlocks;
        int node = nb * (BT / 16) + ((int)threadIdx.x >> 4);
        int j = threadIdx.x & 15;
        if (node >= N) return;
        float4 v = *((const float4*)(x + (size_t)node * D) + j);
        float s = v.x * v.x + v.y * v.y + v.z * v.z + v.w * v.w;
#pragma unroll
        for (int m = 1; m < 16; m <<= 1)
            s += __shfl_xor(s, m, 64);   // reduce within aligned 16-lane group
        float pn = fmaxf(sqrtf(s), MIN_NORM);
        float f = fast_artanh(pn) / pn;
        ushort4 o;
        o.x = f2bf(v.x); o.y = f2bf(v.y); o.z = f2bf(v.z); o.w = f2bf(v.w);
        *((ushort4*)(x_bf + (size_t)node * D) + j) = o;
        if (j == 0) snf[node] = make_float2(s, f);
    }
}

// Kernel 2: one block per 128-row bin, 8 waves, 16 rows per wave (rows are
// the 16 MFMA B-columns). NEW vs R7:
//  (a) rows LENGTH-SORTED (rank-by-count, unique keys) and dealt to waves in
//      sorted-adjacent groups of 16 -> per-wave loop count max(len) ~= mean
//      (kills the ~40% padded iterations of random grouping);
//  (b) 1-deep SOFTWARE PREFETCH: chunk t+1's colsm index + x_bf/snf gathers
//      issue before chunk t's compute -> gather latency hides under
//      MFMA+weight math (the R7 counters showed a bare serial chain:
//      VALU 36%, Mfma 2.6%, HBM 21% -- everything waiting on the gather).
__global__ void fused_kernel(const unsigned short* __restrict__ x_bf,
                             const float2* __restrict__ snf,
                             const unsigned int* __restrict__ binData,
                             const int* __restrict__ cursor,
                             const float* __restrict__ beta,
                             const float* __restrict__ con,
                             float* __restrict__ out, int N) {
    __shared__ int cnt[RPB];
    __shared__ int off[RPB];
    __shared__ int cur[RPB];
    __shared__ int tot[2];
    __shared__ int srt[RPB];
    __shared__ int colsm[BINCAP];

    int b = blockIdx.x;
    int len = min(cursor[b], BINCAP);
    const unsigned int* bd = binData + (size_t)b * BINCAP;

    if (threadIdx.x < RPB) { cnt[threadIdx.x] = 0; cur[threadIdx.x] = 0; }
    if (threadIdx.x == 0) colsm[0] = 0;   // safe slot for empty rows
    __syncthreads();
    for (int i = threadIdx.x; i < len; i += BT)
        atomicAdd(&cnt[bd[i] >> 17], 1);
    __syncthreads();
    if (threadIdx.x < RPB) {   // two-wave exclusive scan of cnt[128]
        int v = cnt[threadIdx.x], inc = v;
#pragma unroll
        for (int m = 1; m < 64; m <<= 1) {
            int t = __shfl_up(inc, m, 64);
            if (((int)threadIdx.x & 63) >= m) inc += t;
        }
        off[threadIdx.x] = inc - v;
        if (((int)threadIdx.x & 63) == 63) tot[threadIdx.x >> 6] = inc;
    }
    __syncthreads();
    if (threadIdx.x >= 64 && threadIdx.x < RPB) off[threadIdx.x] += tot[0];
    // rank rows by length desc (unique key = len<<7 | rl): O(128) serial per
    // thread, broadcast LDS reads (conflict-free), deterministic.
    if (threadIdx.x < RPB) {
        unsigned int myKey = ((unsigned int)cnt[threadIdx.x] << 7) | (unsigned int)threadIdx.x;
        int rank = 0;
        for (int i = 0; i < RPB; ++i) {
            unsigned int k = ((unsigned int)cnt[i] << 7) | (unsigned int)i;
            rank += (k > myKey) ? 1 : 0;
        }
        srt[rank] = threadIdx.x;
    }
    __syncthreads();
    for (int i = threadIdx.x; i < len; i += BT) {
        unsigned int p = bd[i];
        int rl = p >> 17;
        int rk = atomicAdd(&cur[rl], 1);
        colsm[off[rl] + rk] = (int)(p & 0x1FFFFu);
    }
    __syncthreads();

    int wid = threadIdx.x >> 6;          // wave = sorted 16-row group, 0..7
    int lane = threadIdx.x & 63;
    int jj = lane & 15;
    int qd = lane >> 4;
    int src = ((jj >> 2) << 4) | jj;     // lane holding D[jj][jj] in reg (jj&3)
    float Bc = beta[0], C0 = con[0];
    float4_ zero4 = {0.0f, 0.0f, 0.0f, 0.0f};

    int rl = srt[wid * 16 + jj];         // my (sorted) row slot
    int row = b * RPB + rl;
    int rlen = cnt[rl];
    int start = off[rl];
    int safe = rlen > 0 ? start + rlen - 1 : 0;

    // wave-uniform chunk count = max row length over the 16-lane group
    // (sorted-adjacent -> close to the group mean)
    int ml = rlen;
#pragma unroll
    for (int m = 1; m < 16; m <<= 1)
        ml = max(ml, __shfl_xor(ml, m, 64));

    // B operand: lane (qd,jj) holds row jj's features [qd*8,+8) / [32+qd*8,+8)
    const unsigned short* xr = x_bf + (size_t)row * D + qd * 8;
    short8 bfr0 = *(const short8*)xr;    // row>=N: allocated-but-junk, unused
    short8 bfr1 = *(const short8*)(xr + 32);
    float x2 = snf[row].x;

    float acc[16];
#pragma unroll
    for (int i = 0; i < 16; i++) acc[i] = 0.0f;
    float wacc = 0.0f;

    if (ml > 0) {
        // prefetch chunk 0
        int cw = colsm[rlen > 0 ? start : safe];
        const unsigned short* rp = x_bf + (size_t)cw * D + qd * 8;
        short8 caf0 = *(const short8*)rp;
        short8 caf1 = *(const short8*)(rp + 32);
        float2 csf = snf[cw];

        for (int t = 0; t < ml; ++t) {
            // ---- issue prefetch for t+1 (clamped; wave-uniform trip) ----
            int tn = t + 1;
            int idxn = (tn < rlen) ? start + tn : safe;
            int cwn = colsm[idxn];
            const unsigned short* rpn = x_bf + (size_t)cwn * D + qd * 8;
            short8 naf0 = *(const short8*)rpn;
            short8 naf1 = *(const short8*)(rpn + 32);
            float2 nsf = snf[cwn];

            // ---- compute chunk t ----
            bool valid = t < rlen;
            float4_ d4 = __builtin_amdgcn_mfma_f32_16x16x32_bf16(caf0, bfr0, zero4, 0, 0, 0);
            d4 = __builtin_amdgcn_mfma_f32_16x16x32_bf16(caf1, bfr1, d4, 0, 0, 0);
            // D[m][n] = dot(row_m's edge-col, row_n); we need D[jj][jj]

            float sel01 = (jj & 1) ? d4[1] : d4[0];
            float sel23 = (jj & 1) ? d4[3] : d4[2];
            float dsel  = (jj & 2) ? sel23 : sel01;   // my d4[jj&3]
            float d = __shfl(dsel, src, 64);          // = D[jj][jj]

            // weight math (verbatim); all 4 quads of jj compute the same w
            float y2 = csf.x;
            float a_ = 1.0f - 2.0f * d + y2;
            float b_ = 1.0f - x2;
            float num2 = a_ * a_ * x2 - 2.0f * a_ * b_ * d + b_ * b_ * y2;
            float den = fmaxf(1.0f - 2.0f * d + x2 * y2, MIN_NORM);
            float man = sqrtf(fmaxf(num2, 0.0f)) * __builtin_amdgcn_rcpf(den);
            float at = fast_artanh(man);
            float w = __expf(-Bc * 4.0f * at * at + C0);  // dist^2 = 4*artanh^2
            w = valid ? w : 0.0f;
            float wf = w * csf.y;
            wacc += w;
#pragma unroll
            for (int j = 0; j < 8; j++) {
                acc[j]     += wf * bf2f((unsigned short)caf0[j]);
                acc[8 + j] += wf * bf2f((unsigned short)caf1[j]);
            }

            // ---- rotate prefetched regs in ----
            caf0 = naf0; caf1 = naf1; csf = nsf;
        }
    }

    // epilogue: acc is row jj's COMPLETE feature slice; norm = 2-shfl reduce
    // across the 4 quads (disjoint feature ranges).
    float inv = __builtin_amdgcn_rcpf(wacc + 1e-10f);
    float s[16];
    float loc = 0.0f;
#pragma unroll
    for (int j = 0; j < 16; j++) {
        s[j] = acc[j] * inv;
        loc += s[j] * s[j];
    }
    loc += __shfl_xor(loc, 16, 64);
    loc += __shfl_xor(loc, 32, 64);
    float n2 = loc;
    float sq = sqrtf(n2);
    float un = fmaxf(sq, MIN_NORM);
    float e2 = __expf(2.0f * un);        // tanh via exp
    float th = (e2 - 1.0f) * __builtin_amdgcn_rcpf(e2 + 1.0f);
    float tt = th * __builtin_amdgcn_rcpf(un);
    float on = th * sq * __builtin_amdgcn_rcpf(un);   // ||o|| = tt*sq
    float scale = tt;
    if (on > PROJ_MAXNORM)
        scale = tt / fmaxf(on, MIN_NORM) * PROJ_MAXNORM;

    if (row < N) {
        float* op = out + (size_t)row * D;
        float4 v0 = make_float4(scale * s[0],  scale * s[1],  scale * s[2],  scale * s[3]);
        float4 v1 = make_float4(scale * s[4],  scale * s[5],  scale * s[6],  scale * s[7]);
        float4 v2 = make_float4(scale * s[8],  scale * s[9],  scale * s[10], scale * s[11]);
        float4 v3 = make_float4(scale * s[12], scale * s[13], scale * s[14], scale * s[15]);
        *(float4*)(op + qd * 8)          = v0;
        *(float4*)(op + qd * 8 + 4)      = v1;
        *(float4*)(op + 32 + qd * 8)     = v2;
        *(float4*)(op + 32 + qd * 8 + 4) = v3;
    }
}

extern "C" void kernel_launch(void* const* d_in, const int* in_sizes, int n_in,
                              void* d_out, int out_size, void* d_ws, size_t ws_size,
                              hipStream_t stream) {
    const float* x    = (const float*)d_in[0];
    const float* beta = (const float*)d_in[1];
    const float* con  = (const float*)d_in[2];
    const int*   ei   = (const int*)d_in[3];

    int N = in_sizes[0] / D;
    int E = in_sizes[3] / 2;
    const int* row_idx = ei;
    const int* col_idx = ei + E;
    float* out = (float*)d_out;

    int nbins = (N + RPB - 1) / RPB;    // 782 for N=100K (<= MAXBIN)

    // workspace layout (8B-aligned first): ~21.6 MB
    float2*         snf     = (float2*)d_ws;                 // N float2 (800KB)
    unsigned short* x_bf    = (unsigned short*)(snf + N);    // N*D bf16 (12.8 MB)
    unsigned int*   binData = (unsigned int*)(x_bf + (size_t)N * D); // nbins*BINCAP (7.6 MB)
    int*            cursor  = (int*)(binData + (size_t)nbins * BINCAP); // nbins ints (3 KB)

    hipMemsetAsync(cursor, 0, (size_t)nbins * sizeof(int), stream);

    int edgeBlocks = (E + EPB - 1) / EPB;              // 391 for E=1.6M
    int nodeBlocks = (N + (BT / 16) - 1) / (BT / 16);  // 3125

    bin_kernel<<<edgeBlocks + nodeBlocks, BT, 0, stream>>>(
        x, x_bf, snf, row_idx, col_idx, cursor, binData, E, N, nbins, edgeBlocks);

    fused_kernel<<<nbins, BT, 0, stream>>>(x_bf, snf, binData, cursor,
                                           beta, con, out, N);
}